// Round 2
// baseline (771.316 us; speedup 1.0000x reference)
//
#include <hip/hip_runtime.h>
#include <hip/hip_bf16.h>

// MultiHeadAttention: B=4, S=1024, HIDDEN=2048, H=16, d=128, fp32 in/out.
// Pipeline: cast->bf16, QKV gemm, RoPE, V-transpose, QK^T (causal-skipped),
// softmax (+mask) -> fp32 weights in d_out, PV gemm reading fp32 weights
// directly (register convert -> LDS), output projection.
// NT-GEMM template: 128x128 tile, BK=64, 256 thr, mfma_f32_16x16x32_bf16,
// global_load_lds width=16 staging (except MODE 2 A-tile: fp32->bf16 convert).
//
// ws layout (bf16 elems), peak 117,440,512 bytes, lifetimes verified disjoint:
//   Wob  [0,          4194304)   live: cast .. gemm<3>
//   xb   [4194304,   12582912)   live: cast .. gemm<0>
//   Wqkv [12582912,  25165824)   live: cast .. gemm<0>
//   QKV  [25165824,  50331648)   live: gemm<0> .. gemm<1> (V until transpose)
//   Vt   [50331648,  58720256)   live: transpose .. gemm<2>
//   AO   [4194304,   12582912)   overlays dead xb; live: gemm<2> .. gemm<3>

typedef __attribute__((ext_vector_type(8))) short bf16x8;
typedef __attribute__((ext_vector_type(4))) float f32x4;

#define GLD_LDS16(g, l)                                                      \
  __builtin_amdgcn_global_load_lds(                                          \
      (const __attribute__((address_space(1))) unsigned int*)(g),            \
      (__attribute__((address_space(3))) unsigned int*)(l), 16, 0, 0)

// ---------------------------------------------------------------- cast fp32->bf16
__global__ __launch_bounds__(256) void cast_kernel(
    const float* __restrict__ in, __hip_bfloat16* __restrict__ out, int n8) {
  int idx = blockIdx.x * 256 + threadIdx.x;
  if (idx >= n8) return;
  const float4* p = (const float4*)in;
  float4 a = p[idx * 2], b = p[idx * 2 + 1];
  __hip_bfloat16 h[8] = {__float2bfloat16(a.x), __float2bfloat16(a.y),
                         __float2bfloat16(a.z), __float2bfloat16(a.w),
                         __float2bfloat16(b.x), __float2bfloat16(b.y),
                         __float2bfloat16(b.z), __float2bfloat16(b.w)};
  uint4 u;
  __builtin_memcpy(&u, h, 16);
  ((uint4*)out)[idx] = u;
}

// ---------------------------------------------------------------- NT GEMM
// C[m,n] = scale * sum_k A[m,k] * B[n,k]
// MODE 0: QKV proj, z in {0,1,2}. M=4096 N=2048 K=2048, bf16 out
// MODE 1: scores, z=b*16+h. M=N=1024 K=128, fp32 out (*1/sqrt(128)), causal skip
// MODE 2: PV, z=b*16+h. A=fp32 weights[1024,1024] (d_out), B=Vt[128,1024],
//         K=m0+128 (P zero past diagonal), bf16 out
// MODE 3: out proj. M=4096 N=2048 K=2048, fp32 out
template <int MODE>
__global__ __launch_bounds__(256) void gemm_nt(
    const void* __restrict__ Abase, const __hip_bfloat16* __restrict__ Bbase,
    void* __restrict__ Cbase) {
  __shared__ alignas(16) __hip_bfloat16 lA[128][64];
  __shared__ alignas(16) __hip_bfloat16 lB[128][64];

  const int tid = threadIdx.x;
  const int m0 = blockIdx.y * 128;
  const int n0 = blockIdx.x * 128;
  const int z = blockIdx.z;

  const __hip_bfloat16* A = nullptr;
  const float* A32 = nullptr;
  const __hip_bfloat16* Bm;
  int lda = 2048, ldb = 2048, K = 2048;
  if constexpr (MODE == 0) {
    A = (const __hip_bfloat16*)Abase;
    Bm = Bbase + (size_t)z * (2048 * 2048);
  } else if constexpr (MODE == 1) {
    if (n0 > m0) return;  // tile fully above causal diagonal
    int b = z >> 4, h = z & 15;
    A = (const __hip_bfloat16*)Abase + ((size_t)b * 1024) * 2048 + h * 128;
    Bm = Bbase + ((size_t)b * 1024) * 2048 + h * 128;
    K = 128;
  } else if constexpr (MODE == 2) {
    A32 = (const float*)Abase + (size_t)z * (1024 * 1024);
    Bm = Bbase + (size_t)z * (128 * 1024);
    ldb = 1024;
    K = m0 + 128;  // weights are zero past the diagonal
  } else {
    A = (const __hip_bfloat16*)Abase;
    Bm = Bbase;
  }

  const int lane = tid & 63;
  const int wid = tid >> 6;
  const int wm = (wid & 1) * 64;
  const int wn = (wid >> 1) * 64;
  const int frow = lane & 15;
  const int fk = (lane >> 4) * 8;

  f32x4 acc[4][4] = {};

  for (int k0 = 0; k0 < K; k0 += 64) {
    __syncthreads();
    if constexpr (MODE == 2) {
      // A tile: fp32 scores -> bf16 via registers -> LDS (128x64)
#pragma unroll
      for (int c = 0; c < 8; ++c) {
        int lin = c * 256 + tid;
        int r = lin >> 4;
        int col = (lin & 15) << 2;
        float4 v = *(const float4*)&A32[(size_t)(m0 + r) * 1024 + k0 + col];
        __hip_bfloat16 hh[4] = {__float2bfloat16(v.x), __float2bfloat16(v.y),
                                __float2bfloat16(v.z), __float2bfloat16(v.w)};
        unsigned long long u;
        __builtin_memcpy(&u, hh, 8);
        *(unsigned long long*)&lA[r][col] = u;
      }
    } else {
#pragma unroll
      for (int c = 0; c < 4; ++c) {
        int lin = c * 256 + tid;
        int r = lin >> 3;
        int col = (lin & 7) << 3;
        GLD_LDS16(A + (size_t)(m0 + r) * lda + k0 + col, &lA[r][col]);
      }
    }
#pragma unroll
    for (int c = 0; c < 4; ++c) {
      int lin = c * 256 + tid;
      int r = lin >> 3;
      int col = (lin & 7) << 3;
      GLD_LDS16(Bm + (size_t)(n0 + r) * ldb + k0 + col, &lB[r][col]);
    }
    __syncthreads();
#pragma unroll
    for (int kk = 0; kk < 64; kk += 32) {
      bf16x8 av[4], bv[4];
#pragma unroll
      for (int i = 0; i < 4; ++i)
        av[i] = *(const bf16x8*)&lA[wm + i * 16 + frow][kk + fk];
#pragma unroll
      for (int i = 0; i < 4; ++i)
        bv[i] = *(const bf16x8*)&lB[wn + i * 16 + frow][kk + fk];
#pragma unroll
      for (int mi = 0; mi < 4; ++mi)
#pragma unroll
        for (int ni = 0; ni < 4; ++ni)
          acc[mi][ni] = __builtin_amdgcn_mfma_f32_16x16x32_bf16(
              av[mi], bv[ni], acc[mi][ni], 0, 0, 0);
    }
  }

  // C/D layout: col = lane&15, row = (lane>>4)*4 + reg
  const int r0 = (lane >> 4) * 4;
  const int cc = lane & 15;

  if constexpr (MODE == 1) {
    float* C = (float*)Cbase + (size_t)z * (1024 * 1024);
    const float scale = 0.08838834764831845f;  // 1/sqrt(128)
#pragma unroll
    for (int mi = 0; mi < 4; ++mi)
#pragma unroll
      for (int ni = 0; ni < 4; ++ni)
#pragma unroll
        for (int r = 0; r < 4; ++r)
          C[(size_t)(m0 + wm + mi * 16 + r0 + r) * 1024 +
            (n0 + wn + ni * 16 + cc)] = acc[mi][ni][r] * scale;
  } else if constexpr (MODE == 3) {
    float* C = (float*)Cbase;
#pragma unroll
    for (int mi = 0; mi < 4; ++mi)
#pragma unroll
      for (int ni = 0; ni < 4; ++ni)
#pragma unroll
        for (int r = 0; r < 4; ++r)
          C[(size_t)(m0 + wm + mi * 16 + r0 + r) * 2048 +
            (n0 + wn + ni * 16 + cc)] = acc[mi][ni][r];
  } else if constexpr (MODE == 0) {
    __hip_bfloat16* C = (__hip_bfloat16*)Cbase + (size_t)z * (4096 * 2048);
#pragma unroll
    for (int mi = 0; mi < 4; ++mi)
#pragma unroll
      for (int ni = 0; ni < 4; ++ni)
#pragma unroll
        for (int r = 0; r < 4; ++r)
          C[(size_t)(m0 + wm + mi * 16 + r0 + r) * 2048 +
            (n0 + wn + ni * 16 + cc)] = __float2bfloat16(acc[mi][ni][r]);
  } else {  // MODE 2: write attn_out[b, i, h*128 + d]
    int b = z >> 4, h = z & 15;
    __hip_bfloat16* C =
        (__hip_bfloat16*)Cbase + ((size_t)b * 1024) * 2048 + h * 128;
#pragma unroll
    for (int mi = 0; mi < 4; ++mi)
#pragma unroll
      for (int ni = 0; ni < 4; ++ni)
#pragma unroll
        for (int r = 0; r < 4; ++r)
          C[(size_t)(m0 + wm + mi * 16 + r0 + r) * 2048 +
            (n0 + wn + ni * 16 + cc)] = __float2bfloat16(acc[mi][ni][r]);
  }
}

// ---------------------------------------------------------------- RoPE (in place, Llama half-split)
__global__ __launch_bounds__(256) void rope_kernel(__hip_bfloat16* __restrict__ Qb,
                                                   __hip_bfloat16* __restrict__ Kb) {
  __hip_bfloat16* p = blockIdx.y ? Kb : Qb;
  int idx = blockIdx.x * 256 + threadIdx.x;  // 0 .. 4*1024*16*64-1
  int j = idx & 63;
  int h = (idx >> 6) & 15;
  int spos = (idx >> 10) & 1023;
  int b = idx >> 20;
  // inv_freq = 10000^(-2j/128)
  float inv_freq = __expf(-((float)(2 * j) / 128.f) * 9.210340371976184f);
  float ang = (float)spos * inv_freq;
  float c = cosf(ang), sn = sinf(ang);
  size_t base = ((size_t)(b * 1024 + spos)) * 2048 + h * 128 + j;
  float x1 = __bfloat162float(p[base]);
  float x2 = __bfloat162float(p[base + 64]);
  p[base] = __float2bfloat16(x1 * c - x2 * sn);
  p[base + 64] = __float2bfloat16(x2 * c + x1 * sn);
}

// ---------------------------------------------------------------- V transpose [b,s,h,d] -> [b,h,d,s]
__global__ __launch_bounds__(256) void transpose_v(
    const __hip_bfloat16* __restrict__ Vb, __hip_bfloat16* __restrict__ Vt) {
  __shared__ __hip_bfloat16 t[64][65];
  int s0 = blockIdx.x * 64;
  int j0 = blockIdx.y * 64;
  int bh = blockIdx.z;
  int b = bh >> 4, h = bh & 15;
  const __hip_bfloat16* src = Vb + ((size_t)b * 1024) * 2048 + h * 128;
#pragma unroll
  for (int it = 0; it < 16; ++it) {
    int lin = it * 256 + threadIdx.x;
    int r = lin >> 6, c = lin & 63;
    t[r][c] = src[(size_t)(s0 + r) * 2048 + j0 + c];
  }
  __syncthreads();
  __hip_bfloat16* dst = Vt + ((size_t)bh * 128 + j0) * 1024 + s0;
#pragma unroll
  for (int it = 0; it < 16; ++it) {
    int lin = it * 256 + threadIdx.x;
    int r = lin >> 6, c = lin & 63;
    dst[(size_t)r * 1024 + c] = t[c][r];
  }
}

// ---------------------------------------------------------------- causal softmax rows (in place in d_out)
__global__ __launch_bounds__(256) void softmax_kernel(
    float* __restrict__ scores, const float* __restrict__ mask) {
  const int row = blockIdx.x;  // (b*16+h)*1024 + i
  const int i = row & 1023;
  const int b = row >> 14;
  float* srow = scores + (size_t)row * 1024;
  const float* mrow = mask + b * 1024;
  const int tid = threadIdx.x;

  float s[4];
  float mx = -3.0e38f;
#pragma unroll
  for (int it = 0; it < 4; ++it) {
    int j = it * 256 + tid;
    float v = -3.0e38f;
    if (j <= i) v = srow[j] + mrow[j];
    s[it] = v;
    mx = fmaxf(mx, v);
  }
#pragma unroll
  for (int off = 32; off > 0; off >>= 1) mx = fmaxf(mx, __shfl_down(mx, off, 64));
  __shared__ float redm[4], reds[4];
  if ((tid & 63) == 0) redm[tid >> 6] = mx;
  __syncthreads();
  mx = fmaxf(fmaxf(redm[0], redm[1]), fmaxf(redm[2], redm[3]));

  float sum = 0.f;
#pragma unroll
  for (int it = 0; it < 4; ++it) {
    float e = (s[it] > -1.0e38f) ? __expf(s[it] - mx) : 0.f;
    s[it] = e;
    sum += e;
  }
#pragma unroll
  for (int off = 32; off > 0; off >>= 1) sum += __shfl_down(sum, off, 64);
  if ((tid & 63) == 0) reds[tid >> 6] = sum;
  __syncthreads();
  sum = reds[0] + reds[1] + reds[2] + reds[3];
  float inv = 1.0f / sum;
#pragma unroll
  for (int it = 0; it < 4; ++it) {
    int j = it * 256 + tid;
    srow[j] = s[it] * inv;  // zeros past diagonal
  }
}

// ---------------------------------------------------------------- launch
extern "C" void kernel_launch(void* const* d_in, const int* in_sizes, int n_in,
                              void* d_out, int out_size, void* d_ws,
                              size_t ws_size, hipStream_t stream) {
  const float* x = (const float*)d_in[0];
  const float* mask = (const float*)d_in[1];
  const float* Wq = (const float*)d_in[2];
  const float* Wk = (const float*)d_in[3];
  const float* Wv = (const float*)d_in[4];
  const float* Wo = (const float*)d_in[5];
  float* out = (float*)d_out;
  float* attnw = out + (size_t)4 * 1024 * 2048;  // fp32 weights region of d_out

  __hip_bfloat16* wsb = (__hip_bfloat16*)d_ws;
  __hip_bfloat16* Wob = wsb;                 //  4,194,304
  __hip_bfloat16* xb  = wsb + 4194304;       //  8,388,608
  __hip_bfloat16* Wqb = wsb + 12582912;      //  3x 4,194,304 (Wq,Wk,Wv contig)
  __hip_bfloat16* Qb  = wsb + 25165824;      //  3x 8,388,608 (Q,K,V contig)
  __hip_bfloat16* Kb  = wsb + 33554432;
  __hip_bfloat16* Vb  = wsb + 41943040;
  __hip_bfloat16* Vt  = wsb + 50331648;      //  8,388,608
  __hip_bfloat16* AO  = wsb + 4194304;       //  8,388,608 (overlays dead xb)

  cast_kernel<<<4096, 256, 0, stream>>>(x, xb, 1048576);
  cast_kernel<<<2048, 256, 0, stream>>>(Wq, Wqb, 524288);
  cast_kernel<<<2048, 256, 0, stream>>>(Wk, Wqb + 4194304, 524288);
  cast_kernel<<<2048, 256, 0, stream>>>(Wv, Wqb + 8388608, 524288);
  cast_kernel<<<2048, 256, 0, stream>>>(Wo, Wob, 524288);

  gemm_nt<0><<<dim3(16, 32, 3), 256, 0, stream>>>(xb, Wqb, Qb);
  rope_kernel<<<dim3(16384, 2), 256, 0, stream>>>(Qb, Kb);
  transpose_v<<<dim3(16, 2, 64), 256, 0, stream>>>(Vb, Vt);
  gemm_nt<1><<<dim3(8, 8, 64), 256, 0, stream>>>(Qb, Kb, attnw);
  softmax_kernel<<<65536, 256, 0, stream>>>(attnw, mask);
  gemm_nt<2><<<dim3(1, 8, 64), 256, 0, stream>>>(attnw, Vt, AO);
  gemm_nt<3><<<dim3(16, 32, 1), 256, 0, stream>>>(AO, Wob, out);
}